// Round 1
// baseline (9505.378 us; speedup 1.0000x reference)
//
#include <hip/hip_runtime.h>
#include <math.h>

#define NN 100000
#define NE 1600000
#define ET (NN + NE)

__device__ __forceinline__ unsigned fflip(float f) {
  unsigned u = __float_as_uint(f);
  return (u & 0x80000000u) ? ~u : (u | 0x80000000u);
}
__device__ __forceinline__ float funflip(unsigned v) {
  return __uint_as_float((v & 0x80000000u) ? (v ^ 0x80000000u) : ~v);
}

// h[n, 0:128] = x[n, 0:K] @ W[K, 128]
template <int K>
__global__ __launch_bounds__(256) void gemm_k(const float* __restrict__ x,
                                              const float* __restrict__ W,
                                              float* __restrict__ h) {
  __shared__ float Ws[64 * 128];
  __shared__ float xs[8][64];
  const int t = threadIdx.x;
  const int row0 = blockIdx.x * 8;
  const int r = t >> 5;         // 0..7
  const int c4 = (t & 31) * 4;  // 0..124
  float4 acc = {0.f, 0.f, 0.f, 0.f};
  for (int kc = 0; kc < K; kc += 64) {
    const float4* Wg = (const float4*)(W + kc * 128);
    float4* Wl = (float4*)Ws;
#pragma unroll
    for (int i = 0; i < 8; i++) Wl[t + i * 256] = Wg[t + i * 256];
    {
      int idx = t * 2;
      int rr = idx >> 6, cc = idx & 63;
      int grow = row0 + rr;
      float2 v = {0.f, 0.f};
      if (grow < NN) v = *(const float2*)(x + (size_t)grow * K + kc + cc);
      *(float2*)&xs[rr][cc] = v;
    }
    __syncthreads();
#pragma unroll
    for (int k = 0; k < 64; k++) {
      float xv = xs[r][k];
      float4 w = *(float4*)(Ws + k * 128 + c4);
      acc.x += xv * w.x;
      acc.y += xv * w.y;
      acc.z += xv * w.z;
      acc.w += xv * w.w;
    }
    __syncthreads();
  }
  int grow = row0 + r;
  if (grow < NN) *(float4*)(h + (size_t)grow * 128 + c4) = acc;
}

// per-node attention dots
template <int H, int C>
__global__ void alpha_k(const float* __restrict__ h, const float* __restrict__ a_s,
                        const float* __restrict__ a_d, float* __restrict__ os,
                        float* __restrict__ od) {
  int n = blockIdx.x * blockDim.x + threadIdx.x;
  if (n >= NN) return;
  float as[H], ad[H];
#pragma unroll
  for (int i = 0; i < H; i++) { as[i] = 0.f; ad[i] = 0.f; }
#pragma unroll
  for (int c = 0; c < 128; c += 4) {
    float4 hv = *(const float4*)(h + (size_t)n * 128 + c);
    float4 sv = *(const float4*)(a_s + c);
    float4 dv = *(const float4*)(a_d + c);
    const int hh = c / C;
    as[hh] += hv.x * sv.x + hv.y * sv.y + hv.z * sv.z + hv.w * sv.w;
    ad[hh] += hv.x * dv.x + hv.y * dv.y + hv.z * dv.z + hv.w * dv.w;
  }
#pragma unroll
  for (int i = 0; i < H; i++) {
    os[n * H + i] = as[i];
    od[n * H + i] = ad[i];
  }
}

// edge pass 1: logits + segment max (flipped-uint atomicMax)
template <int H>
__global__ void edge1_k(const int* __restrict__ ei, const float* __restrict__ as,
                        const float* __restrict__ ad, float* __restrict__ logit,
                        unsigned* __restrict__ mflip) {
  int idx = blockIdx.x * blockDim.x + threadIdx.x;
  if (idx >= ET * H) return;
  int e = idx / H, hh = idx % H;
  int s, d;
  if (e < NE) { s = ei[e]; d = ei[NE + e]; } else { s = d = e - NE; }
  float lg = as[s * H + hh] + ad[d * H + hh];
  lg = lg > 0.f ? lg : 0.2f * lg;
  logit[(size_t)e * H + hh] = lg;
  atomicMax(&mflip[d * H + hh], fflip(lg));
}

// edge pass 2: ex, denom accumulate, unnormalized weighted aggregation
template <int H, int C>
__global__ __launch_bounds__(256) void edge2_k(const int* __restrict__ ei,
                                               const float* __restrict__ logit,
                                               const unsigned* __restrict__ mflip,
                                               const float* __restrict__ h,
                                               float* __restrict__ denom,
                                               float* __restrict__ num) {
  int t = blockIdx.x * 256 + threadIdx.x;
  int e = t >> 5;
  if (e >= ET) return;
  int l = t & 31;
  int s, d;
  if (e < NE) { s = ei[e]; d = ei[NE + e]; } else { s = d = e - NE; }
  int c4 = l * 4;
  int hh = c4 / C;
  float m = funflip(mflip[d * H + hh]);
  float ex = __expf(logit[(size_t)e * H + hh] - m);
  if ((c4 & (C - 1)) == 0) atomicAdd(&denom[d * H + hh], ex);
  float4 hv = *(const float4*)(h + (size_t)s * 128 + c4);
  float* np = num + (size_t)d * 128 + c4;
  atomicAdd(np + 0, ex * hv.x);
  atomicAdd(np + 1, ex * hv.y);
  atomicAdd(np + 2, ex * hv.z);
  atomicAdd(np + 3, ex * hv.w);
}

// y = num/denom + b (in place), per-channel partial BN sums
template <int H, int C>
__global__ __launch_bounds__(256) void bn1_k(float* __restrict__ y,
                                             const float* __restrict__ denom,
                                             const float* __restrict__ bvec,
                                             float* __restrict__ bnred) {
  __shared__ float red[256];
  int c = threadIdx.x & 127;
  int sub = threadIdx.x >> 7;
  int n0 = blockIdx.x * 64;
  float s1 = 0.f, s2 = 0.f;
  const int hh = c / C;
  float bc = bvec[c];
  for (int k = 0; k < 32; k++) {
    int n = n0 + sub + k * 2;
    if (n < NN) {
      float v = y[(size_t)n * 128 + c] / (denom[n * H + hh] + 1e-16f) + bc;
      y[(size_t)n * 128 + c] = v;
      s1 += v;
      s2 += v * v;
    }
  }
  red[threadIdx.x] = s1;
  __syncthreads();
  if (sub == 0) atomicAdd(&bnred[c], s1 + red[threadIdx.x + 128]);
  __syncthreads();
  red[threadIdx.x] = s2;
  __syncthreads();
  if (sub == 0) atomicAdd(&bnred[128 + c], s2 + red[threadIdx.x + 128]);
}

__global__ void bn2_k(const float* __restrict__ bnred, const float* __restrict__ g,
                      const float* __restrict__ be, float* __restrict__ scale,
                      float* __restrict__ shift) {
  int c = threadIdx.x;
  float mean = bnred[c] / (float)NN;
  float var = bnred[128 + c] / (float)NN - mean * mean;
  float inv = rsqrtf(var + 1e-5f);
  float sc = g[c] * inv;
  scale[c] = sc;
  shift[c] = be[c] - mean * sc;
}

__global__ void bn3_k(const float* __restrict__ y, const float* __restrict__ scale,
                      const float* __restrict__ shift, float* __restrict__ out) {
  int i = blockIdx.x * blockDim.x + threadIdx.x;
  if (i >= NN * 128) return;
  int c = i & 127;
  float v = y[i] * scale[c] + shift[c];
  out[i] = v > 0.f ? v : 0.f;
}

template <int H, int C, int K>
static void run_layer(const float* xin, const int* ei, const float* W,
                      const float* a_s, const float* a_d, const float* bvec,
                      const float* g, const float* be, float* hbuf, float* numbuf,
                      float* logit, float* asrc, float* adst, unsigned* mflip,
                      float* denom, float* bnred, float* scale, float* shift,
                      float* xout, hipStream_t stream) {
  gemm_k<K><<<(NN + 7) / 8, 256, 0, stream>>>(xin, W, hbuf);
  alpha_k<H, C><<<(NN + 255) / 256, 256, 0, stream>>>(hbuf, a_s, a_d, asrc, adst);
  // zero: num accumulator (B buffer, xin already consumed by gemm), and
  // mflip/denom/bnred (contiguous region)
  hipMemsetAsync(numbuf, 0, (size_t)NN * 128 * sizeof(float), stream);
  hipMemsetAsync(mflip, 0, ((size_t)NN * 4 * 2 + 256) * sizeof(float), stream);
  edge1_k<H><<<(ET * H + 255) / 256, 256, 0, stream>>>(ei, asrc, adst, logit, mflip);
  edge2_k<H, C><<<((size_t)ET * 32 + 255) / 256, 256, 0, stream>>>(ei, logit, mflip,
                                                                   hbuf, denom, numbuf);
  bn1_k<H, C><<<(NN + 63) / 64, 256, 0, stream>>>(numbuf, denom, bvec, bnred);
  bn2_k<<<1, 128, 0, stream>>>(bnred, g, be, scale, shift);
  bn3_k<<<(NN * 128 + 255) / 256, 256, 0, stream>>>(numbuf, scale, shift, xout);
}

extern "C" void kernel_launch(void* const* d_in, const int* in_sizes, int n_in,
                              void* d_out, int out_size, void* d_ws, size_t ws_size,
                              hipStream_t stream) {
  (void)in_sizes; (void)n_in; (void)out_size; (void)ws_size;
  const float* x = (const float*)d_in[0];
  const int* ei = (const int*)d_in[1];
  const float* W1 = (const float*)d_in[2];
  const float* as1 = (const float*)d_in[3];
  const float* ad1 = (const float*)d_in[4];
  const float* b1 = (const float*)d_in[5];
  const float* g1 = (const float*)d_in[6];
  const float* be1 = (const float*)d_in[7];
  const float* W2 = (const float*)d_in[8];
  const float* as2 = (const float*)d_in[9];
  const float* ad2 = (const float*)d_in[10];
  const float* b2 = (const float*)d_in[11];
  const float* g2 = (const float*)d_in[12];
  const float* be2 = (const float*)d_in[13];
  const float* W3 = (const float*)d_in[14];
  const float* as3 = (const float*)d_in[15];
  const float* ad3 = (const float*)d_in[16];
  const float* b3 = (const float*)d_in[17];
  const float* g3 = (const float*)d_in[18];
  const float* be3 = (const float*)d_in[19];

  float* A = (float*)d_ws;                    // h buffer       [NN*128]
  float* B = A + (size_t)NN * 128;            // num / y buffer [NN*128]
  float* logit = B + (size_t)NN * 128;        // [ET*4]
  float* asrc = logit + (size_t)ET * 4;       // [NN*4]
  float* adst = asrc + (size_t)NN * 4;        // [NN*4]
  unsigned* mflip = (unsigned*)(adst + (size_t)NN * 4);  // [NN*4]
  float* denom = (float*)(mflip + (size_t)NN * 4);       // [NN*4]
  float* bnred = denom + (size_t)NN * 4;      // [256]
  float* scale = bnred + 256;                 // [128]
  float* shift = scale + 128;                 // [128]

  // Layer 1: x(d_in) -> h(A) -> num(B) -> y(B in place) -> x2(B in place)
  run_layer<4, 32, 64>(x, ei, W1, as1, ad1, b1, g1, be1, A, B, logit, asrc, adst,
                       mflip, denom, bnred, scale, shift, B, stream);
  // Layer 2: x2(B) -> h(A) -> num(B) -> y(B) -> x3(B)
  run_layer<4, 32, 128>(B, ei, W2, as2, ad2, b2, g2, be2, A, B, logit, asrc, adst,
                        mflip, denom, bnred, scale, shift, B, stream);
  // Layer 3: x3(B) -> h(A) -> num(B) -> y(B) -> d_out
  run_layer<1, 128, 128>(B, ei, W3, as3, ad3, b3, g3, be3, A, B, logit, asrc, adst,
                         mflip, denom, bnred, scale, shift, (float*)d_out, stream);
}

// Round 2
// 1326.275 us; speedup vs baseline: 7.1670x; 7.1670x over previous
//
#include <hip/hip_runtime.h>
#include <math.h>

#define NN 100000
#define NE 1600000
#define ET (NN + NE)
#define NB ((NN + 255) / 256)  // scan blocks = 391

// ---------------- GEMM: h[n,0:128] = x[n,0:K] @ W[K,128] ----------------
template <int K>
__global__ __launch_bounds__(256) void gemm_k(const float* __restrict__ x,
                                              const float* __restrict__ W,
                                              float* __restrict__ h) {
  __shared__ float Ws[64 * 128];
  __shared__ float xs[8][64];
  const int t = threadIdx.x;
  const int row0 = blockIdx.x * 8;
  const int r = t >> 5;
  const int c4 = (t & 31) * 4;
  float4 acc = {0.f, 0.f, 0.f, 0.f};
  for (int kc = 0; kc < K; kc += 64) {
    const float4* Wg = (const float4*)(W + kc * 128);
    float4* Wl = (float4*)Ws;
#pragma unroll
    for (int i = 0; i < 8; i++) Wl[t + i * 256] = Wg[t + i * 256];
    {
      int idx = t * 2;
      int rr = idx >> 6, cc = idx & 63;
      int grow = row0 + rr;
      float2 v = {0.f, 0.f};
      if (grow < NN) v = *(const float2*)(x + (size_t)grow * K + kc + cc);
      *(float2*)&xs[rr][cc] = v;
    }
    __syncthreads();
#pragma unroll
    for (int k = 0; k < 64; k++) {
      float xv = xs[r][k];
      float4 w = *(float4*)(Ws + k * 128 + c4);
      acc.x += xv * w.x;
      acc.y += xv * w.y;
      acc.z += xv * w.z;
      acc.w += xv * w.w;
    }
    __syncthreads();
  }
  int grow = row0 + r;
  if (grow < NN) *(float4*)(h + (size_t)grow * 128 + c4) = acc;
}

// ---------------- per-node attention dots ----------------
template <int H, int C>
__global__ void alpha_k(const float* __restrict__ h, const float* __restrict__ a_s,
                        const float* __restrict__ a_d, float* __restrict__ os,
                        float* __restrict__ od) {
  int n = blockIdx.x * blockDim.x + threadIdx.x;
  if (n >= NN) return;
  float as[H], ad[H];
#pragma unroll
  for (int i = 0; i < H; i++) { as[i] = 0.f; ad[i] = 0.f; }
#pragma unroll
  for (int c = 0; c < 128; c += 4) {
    float4 hv = *(const float4*)(h + (size_t)n * 128 + c);
    float4 sv = *(const float4*)(a_s + c);
    float4 dv = *(const float4*)(a_d + c);
    const int hh = c / C;
    as[hh] += hv.x * sv.x + hv.y * sv.y + hv.z * sv.z + hv.w * sv.w;
    ad[hh] += hv.x * dv.x + hv.y * dv.y + hv.z * dv.z + hv.w * dv.w;
  }
#pragma unroll
  for (int i = 0; i < H; i++) {
    os[n * H + i] = as[i];
    od[n * H + i] = ad[i];
  }
}

// ---------------- CSR build (once per call, reused by all 3 layers) ----------------
__global__ void init_cnt_k(int* __restrict__ cnt) {
  int i = blockIdx.x * blockDim.x + threadIdx.x;
  if (i < NN) cnt[i] = 1;  // self-loop
}

__global__ void hist_k(const int* __restrict__ ei, int* __restrict__ cnt) {
  int e = blockIdx.x * blockDim.x + threadIdx.x;
  if (e < NE) atomicAdd(&cnt[ei[NE + e]], 1);
}

// exclusive scan within 256-block; block totals to part[]
__global__ void scan1_k(const int* __restrict__ cnt, int* __restrict__ rowptr,
                        int* __restrict__ part) {
  __shared__ int tmp[256];
  int t = threadIdx.x;
  int i = blockIdx.x * 256 + t;
  int v = (i < NN) ? cnt[i] : 0;
  tmp[t] = v;
  __syncthreads();
  for (int off = 1; off < 256; off <<= 1) {
    int x = (t >= off) ? tmp[t - off] : 0;
    __syncthreads();
    tmp[t] += x;
    __syncthreads();
  }
  if (i < NN) rowptr[i] = tmp[t] - v;
  if (t == 255) part[blockIdx.x] = tmp[255];
}

__global__ void scan2_k(int* __restrict__ part) {
  __shared__ int tmp[512];
  int t = threadIdx.x;
  int v = (t < NB) ? part[t] : 0;
  tmp[t] = v;
  __syncthreads();
  for (int off = 1; off < 512; off <<= 1) {
    int x = (t >= off) ? tmp[t - off] : 0;
    __syncthreads();
    tmp[t] += x;
    __syncthreads();
  }
  if (t < NB) part[t] = tmp[t] - v;
}

__global__ void scan3_k(int* __restrict__ rowptr, const int* __restrict__ part,
                        int* __restrict__ pos) {
  int i = blockIdx.x * blockDim.x + threadIdx.x;
  if (i < NN) {
    int r = rowptr[i] + part[i >> 8];
    rowptr[i] = r;
    pos[i] = r;
  }
  if (i == 0) rowptr[NN] = ET;
}

__global__ void scatter_k(const int* __restrict__ ei, int* __restrict__ pos,
                          int* __restrict__ srcs) {
  int e = blockIdx.x * blockDim.x + threadIdx.x;
  if (e >= ET) return;
  int s, d;
  if (e < NE) { s = ei[e]; d = ei[NE + e]; } else { s = d = e - NE; }
  int p = atomicAdd(&pos[d], 1);
  srcs[p] = s;
}

// ---------------- fused GAT aggregation: one block (128 thr) per dst node ----------------
// computes segment max, softmax, weighted gather-aggregate, bias. No float atomics.
template <int H, int C>
__global__ __launch_bounds__(128) void gat_agg_k(
    const int* __restrict__ rowptr, const int* __restrict__ srcs,
    const float* __restrict__ as, const float* __restrict__ ad,
    const float* __restrict__ h, const float* __restrict__ bvec,
    float* __restrict__ y) {
  const int d = blockIdx.x;
  const int t = threadIdx.x;  // channel 0..127
  const int r0 = rowptr[d], r1 = rowptr[d + 1];

  __shared__ float red[128];
  __shared__ int ssh[128];
  __shared__ float exsh[128 * H];
  __shared__ float mh[H];
  __shared__ float dh[H];

  float adl[H];
#pragma unroll
  for (int hh = 0; hh < H; hh++) adl[hh] = ad[d * H + hh];

  // pass 1: per-head max over incoming edges
  float mx[H];
#pragma unroll
  for (int hh = 0; hh < H; hh++) mx[hh] = -INFINITY;
  for (int e = r0 + t; e < r1; e += 128) {
    int s = srcs[e];
#pragma unroll
    for (int hh = 0; hh < H; hh++) {
      float lg = as[s * H + hh] + adl[hh];
      lg = lg > 0.f ? lg : 0.2f * lg;
      mx[hh] = fmaxf(mx[hh], lg);
    }
  }
#pragma unroll
  for (int hh = 0; hh < H; hh++) {
    red[t] = mx[hh];
    __syncthreads();
    for (int s = 64; s > 0; s >>= 1) {
      if (t < s) red[t] = fmaxf(red[t], red[t + s]);
      __syncthreads();
    }
    if (t == 0) mh[hh] = red[0];
    __syncthreads();
  }

  // pass 2: chunked exp + denom partials + channel-parallel aggregate
  const int hc = t / C;
  float acc = 0.f;
  float dsum[H];
#pragma unroll
  for (int hh = 0; hh < H; hh++) dsum[hh] = 0.f;

  for (int base = r0; base < r1; base += 128) {
    int cnt = min(128, r1 - base);
    if (t < cnt) {
      int s = srcs[base + t];
      ssh[t] = s;
#pragma unroll
      for (int hh = 0; hh < H; hh++) {
        float lg = as[s * H + hh] + adl[hh];
        lg = lg > 0.f ? lg : 0.2f * lg;
        float ex = __expf(lg - mh[hh]);
        exsh[t * H + hh] = ex;
        dsum[hh] += ex;
      }
    }
    __syncthreads();
    for (int j = 0; j < cnt; j++) {
      acc += exsh[j * H + hc] * h[(size_t)ssh[j] * 128 + t];
    }
    __syncthreads();
  }

#pragma unroll
  for (int hh = 0; hh < H; hh++) {
    red[t] = dsum[hh];
    __syncthreads();
    for (int s = 64; s > 0; s >>= 1) {
      if (t < s) red[t] += red[t + s];
      __syncthreads();
    }
    if (t == 0) dh[hh] = red[0];
    __syncthreads();
  }

  y[(size_t)d * 128 + t] = acc / (dh[hc] + 1e-16f) + bvec[t];
}

// ---------------- BN ----------------
__global__ __launch_bounds__(256) void bn_stats_k(const float* __restrict__ y,
                                                  float* __restrict__ bnred) {
  __shared__ float red[256];
  int c = threadIdx.x & 127;
  int sub = threadIdx.x >> 7;
  int n0 = blockIdx.x * 64;
  float s1 = 0.f, s2 = 0.f;
  for (int k = 0; k < 32; k++) {
    int n = n0 + sub + k * 2;
    if (n < NN) {
      float v = y[(size_t)n * 128 + c];
      s1 += v;
      s2 += v * v;
    }
  }
  red[threadIdx.x] = s1;
  __syncthreads();
  if (sub == 0) atomicAdd(&bnred[c], s1 + red[threadIdx.x + 128]);
  __syncthreads();
  red[threadIdx.x] = s2;
  __syncthreads();
  if (sub == 0) atomicAdd(&bnred[128 + c], s2 + red[threadIdx.x + 128]);
}

__global__ void bn2_k(const float* __restrict__ bnred, const float* __restrict__ g,
                      const float* __restrict__ be, float* __restrict__ scale,
                      float* __restrict__ shift) {
  int c = threadIdx.x;
  float mean = bnred[c] / (float)NN;
  float var = bnred[128 + c] / (float)NN - mean * mean;
  float inv = rsqrtf(var + 1e-5f);
  float sc = g[c] * inv;
  scale[c] = sc;
  shift[c] = be[c] - mean * sc;
}

__global__ void bn3_k(const float* __restrict__ y, const float* __restrict__ scale,
                      const float* __restrict__ shift, float* __restrict__ out) {
  int i = blockIdx.x * blockDim.x + threadIdx.x;
  if (i >= NN * 128) return;
  int c = i & 127;
  float v = y[i] * scale[c] + shift[c];
  out[i] = v > 0.f ? v : 0.f;
}

// ---------------- layer driver ----------------
template <int H, int C, int K>
static void run_layer(const float* xin, const int* rowptr, const int* srcs,
                      const float* W, const float* a_s, const float* a_d,
                      const float* bvec, const float* g, const float* be,
                      float* hbuf, float* ybuf, float* asrc, float* adst,
                      float* bnred, float* scale, float* shift, float* xout,
                      hipStream_t stream) {
  gemm_k<K><<<(NN + 7) / 8, 256, 0, stream>>>(xin, W, hbuf);
  alpha_k<H, C><<<(NN + 255) / 256, 256, 0, stream>>>(hbuf, a_s, a_d, asrc, adst);
  gat_agg_k<H, C><<<NN, 128, 0, stream>>>(rowptr, srcs, asrc, adst, hbuf, bvec, ybuf);
  hipMemsetAsync(bnred, 0, 256 * sizeof(float), stream);
  bn_stats_k<<<(NN + 63) / 64, 256, 0, stream>>>(ybuf, bnred);
  bn2_k<<<1, 128, 0, stream>>>(bnred, g, be, scale, shift);
  bn3_k<<<(NN * 128 + 255) / 256, 256, 0, stream>>>(ybuf, scale, shift, xout);
}

extern "C" void kernel_launch(void* const* d_in, const int* in_sizes, int n_in,
                              void* d_out, int out_size, void* d_ws, size_t ws_size,
                              hipStream_t stream) {
  (void)in_sizes; (void)n_in; (void)out_size; (void)ws_size;
  const float* x = (const float*)d_in[0];
  const int* ei = (const int*)d_in[1];
  const float* W1 = (const float*)d_in[2];
  const float* as1 = (const float*)d_in[3];
  const float* ad1 = (const float*)d_in[4];
  const float* b1 = (const float*)d_in[5];
  const float* g1 = (const float*)d_in[6];
  const float* be1 = (const float*)d_in[7];
  const float* W2 = (const float*)d_in[8];
  const float* as2 = (const float*)d_in[9];
  const float* ad2 = (const float*)d_in[10];
  const float* b2 = (const float*)d_in[11];
  const float* g2 = (const float*)d_in[12];
  const float* be2 = (const float*)d_in[13];
  const float* W3 = (const float*)d_in[14];
  const float* as3 = (const float*)d_in[15];
  const float* ad3 = (const float*)d_in[16];
  const float* b3 = (const float*)d_in[17];
  const float* g3 = (const float*)d_in[18];
  const float* be3 = (const float*)d_in[19];

  float* A = (float*)d_ws;                   // h buffer  [NN*128]
  float* B = A + (size_t)NN * 128;           // y buffer  [NN*128]
  float* asrc = B + (size_t)NN * 128;        // [NN*4]
  float* adst = asrc + (size_t)NN * 4;       // [NN*4]
  float* bnred = adst + (size_t)NN * 4;      // [256]
  float* scale = bnred + 256;                // [128]
  float* shift = scale + 128;                // [128]
  int* rowptr = (int*)(shift + 128);         // [NN+1]
  int* cnt = rowptr + NN + 2;                // [NN]
  int* pos = cnt + NN;                       // [NN]
  int* part = pos + NN;                      // [512]
  int* srcs = part + 512;                    // [ET]

  // ---- CSR build (edges shared by all layers) ----
  init_cnt_k<<<(NN + 255) / 256, 256, 0, stream>>>(cnt);
  hist_k<<<(NE + 255) / 256, 256, 0, stream>>>(ei, cnt);
  scan1_k<<<NB, 256, 0, stream>>>(cnt, rowptr, part);
  scan2_k<<<1, 512, 0, stream>>>(part);
  scan3_k<<<(NN + 255) / 256, 256, 0, stream>>>(rowptr, part, pos);
  scatter_k<<<(ET + 255) / 256, 256, 0, stream>>>(ei, pos, srcs);

  // Layer 1: x -> h(A) -> y(B)
  run_layer<4, 32, 64>(x, rowptr, srcs, W1, as1, ad1, b1, g1, be1, A, B, asrc,
                       adst, bnred, scale, shift, B, stream);
  // Layer 2: x2(B) -> h(A) -> y(B)
  run_layer<4, 32, 128>(B, rowptr, srcs, W2, as2, ad2, b2, g2, be2, A, B, asrc,
                        adst, bnred, scale, shift, B, stream);
  // Layer 3: x3(B) -> h(A) -> out
  run_layer<1, 128, 128>(B, rowptr, srcs, W3, as3, ad3, b3, g3, be3, A, B, asrc,
                         adst, bnred, scale, shift, (float*)d_out, stream);
}

// Round 3
// 969.232 us; speedup vs baseline: 9.8071x; 1.3684x over previous
//
#include <hip/hip_runtime.h>
#include <math.h>

#define NN 100000
#define NE 1600000
#define ET (NN + NE)
#define NB ((NN + 255) / 256)  // scan blocks = 391

__device__ __forceinline__ unsigned short bf16rne(float f) {
  unsigned u = __float_as_uint(f);
  unsigned r = u + 0x7fffu + ((u >> 16) & 1u);
  return (unsigned short)(r >> 16);
}
__device__ __forceinline__ float bf16tof(unsigned short s) {
  return __uint_as_float((unsigned)s << 16);
}

// ---------------- fused GEMM: h2[n,:] = bf16(BN?(x)[n,:] @ W), alpha dots ----------------
// 64 rows/block, 256 threads, W fully LDS-resident.
template <int K, int H, bool BN>
__global__ __launch_bounds__(256) void gemm_fused_k(
    const float* __restrict__ x, const float* __restrict__ W,
    const float* __restrict__ scale, const float* __restrict__ shift,
    const float* __restrict__ a_s, const float* __restrict__ a_d,
    unsigned short* __restrict__ h2, float* __restrict__ os,
    float* __restrict__ od) {
  __shared__ float Ws[K * 128];
  __shared__ float xs[64][32];
  const int t = threadIdx.x;
  const int row0 = blockIdx.x * 64;
  const int rgrp = t >> 5;   // 0..7 -> rows rgrp*8..rgrp*8+7
  const int j = t & 31;      // channel group
  const int c4 = j * 4;

  {  // stage W once
    const float4* Wg = (const float4*)W;
    float4* Wl = (float4*)Ws;
#pragma unroll
    for (int i = 0; i < K / 8; i++) Wl[t + i * 256] = Wg[t + i * 256];
  }

  float4 acc[8];
#pragma unroll
  for (int i = 0; i < 8; i++) acc[i] = {0.f, 0.f, 0.f, 0.f};

  for (int kc = 0; kc < K; kc += 32) {
    __syncthreads();
    // stage xs[64][32] with optional BN+ReLU applied to the input
#pragma unroll
    for (int ii = 0; ii < 2; ii++) {
      int fi = t * 2 + ii;     // float4 index 0..511
      int r = fi >> 3;         // 0..63
      int cc = (fi & 7) * 4;   // 0..28
      int grow = row0 + r;
      float4 v = {0.f, 0.f, 0.f, 0.f};
      if (grow < NN) {
        v = *(const float4*)(x + (size_t)grow * K + kc + cc);
        if (BN) {
          int c = kc + cc;
          v.x = fmaxf(fmaf(v.x, scale[c + 0], shift[c + 0]), 0.f);
          v.y = fmaxf(fmaf(v.y, scale[c + 1], shift[c + 1]), 0.f);
          v.z = fmaxf(fmaf(v.z, scale[c + 2], shift[c + 2]), 0.f);
          v.w = fmaxf(fmaf(v.w, scale[c + 3], shift[c + 3]), 0.f);
        }
      }
      *(float4*)&xs[r][cc] = v;
    }
    __syncthreads();
#pragma unroll
    for (int k4 = 0; k4 < 8; k4++) {
      float4 w0 = *(float4*)(Ws + (kc + k4 * 4 + 0) * 128 + c4);
      float4 w1 = *(float4*)(Ws + (kc + k4 * 4 + 1) * 128 + c4);
      float4 w2 = *(float4*)(Ws + (kc + k4 * 4 + 2) * 128 + c4);
      float4 w3 = *(float4*)(Ws + (kc + k4 * 4 + 3) * 128 + c4);
#pragma unroll
      for (int i = 0; i < 8; i++) {
        float4 xv = *(float4*)&xs[rgrp * 8 + i][k4 * 4];
        acc[i].x += xv.x * w0.x + xv.y * w1.x + xv.z * w2.x + xv.w * w3.x;
        acc[i].y += xv.x * w0.y + xv.y * w1.y + xv.z * w2.y + xv.w * w3.y;
        acc[i].z += xv.x * w0.z + xv.y * w1.z + xv.z * w2.z + xv.w * w3.z;
        acc[i].w += xv.x * w0.w + xv.y * w1.w + xv.z * w2.w + xv.w * w3.w;
      }
    }
  }

  // epilogue: bf16 h2 store + fused alpha dots
  float4 asv = *(const float4*)(a_s + c4);
  float4 adv = *(const float4*)(a_d + c4);
#pragma unroll
  for (int i = 0; i < 8; i++) {
    int grow = row0 + rgrp * 8 + i;
    bool ok = grow < NN;
    if (ok) {
      ushort4 u;
      u.x = bf16rne(acc[i].x);
      u.y = bf16rne(acc[i].y);
      u.z = bf16rne(acc[i].z);
      u.w = bf16rne(acc[i].w);
      *(ushort4*)(h2 + (size_t)grow * 128 + c4) = u;
    }
    float sdot = acc[i].x * asv.x + acc[i].y * asv.y + acc[i].z * asv.z + acc[i].w * asv.w;
    float ddot = acc[i].x * adv.x + acc[i].y * adv.y + acc[i].z * adv.z + acc[i].w * adv.w;
    if (H == 4) {
      sdot += __shfl_xor(sdot, 1); ddot += __shfl_xor(ddot, 1);
      sdot += __shfl_xor(sdot, 2); ddot += __shfl_xor(ddot, 2);
      sdot += __shfl_xor(sdot, 4); ddot += __shfl_xor(ddot, 4);
      if (ok && (j & 7) == 0) {
        os[grow * 4 + (j >> 3)] = sdot;
        od[grow * 4 + (j >> 3)] = ddot;
      }
    } else {
      sdot += __shfl_xor(sdot, 1); ddot += __shfl_xor(ddot, 1);
      sdot += __shfl_xor(sdot, 2); ddot += __shfl_xor(ddot, 2);
      sdot += __shfl_xor(sdot, 4); ddot += __shfl_xor(ddot, 4);
      sdot += __shfl_xor(sdot, 8); ddot += __shfl_xor(ddot, 8);
      sdot += __shfl_xor(sdot, 16); ddot += __shfl_xor(ddot, 16);
      if (ok && j == 0) {
        os[grow] = sdot;
        od[grow] = ddot;
      }
    }
  }
}

// ---------------- CSR build ----------------
__global__ void init_cnt_k(int* __restrict__ cnt) {
  int i = blockIdx.x * blockDim.x + threadIdx.x;
  if (i < NN) cnt[i] = 1;  // self-loop
}

__global__ void hist_k(const int* __restrict__ ei, int* __restrict__ cnt) {
  int e = blockIdx.x * blockDim.x + threadIdx.x;
  if (e < NE) atomicAdd(&cnt[ei[NE + e]], 1);
}

__global__ void scan1_k(const int* __restrict__ cnt, int* __restrict__ rowptr,
                        int* __restrict__ part) {
  __shared__ int tmp[256];
  int t = threadIdx.x;
  int i = blockIdx.x * 256 + t;
  int v = (i < NN) ? cnt[i] : 0;
  tmp[t] = v;
  __syncthreads();
  for (int off = 1; off < 256; off <<= 1) {
    int x = (t >= off) ? tmp[t - off] : 0;
    __syncthreads();
    tmp[t] += x;
    __syncthreads();
  }
  if (i < NN) rowptr[i] = tmp[t] - v;
  if (t == 255) part[blockIdx.x] = tmp[255];
}

__global__ void scan2_k(int* __restrict__ part) {
  __shared__ int tmp[512];
  int t = threadIdx.x;
  int v = (t < NB) ? part[t] : 0;
  tmp[t] = v;
  __syncthreads();
  for (int off = 1; off < 512; off <<= 1) {
    int x = (t >= off) ? tmp[t - off] : 0;
    __syncthreads();
    tmp[t] += x;
    __syncthreads();
  }
  if (t < NB) part[t] = tmp[t] - v;
}

__global__ void scan3_k(int* __restrict__ rowptr, const int* __restrict__ part,
                        int* __restrict__ pos) {
  int i = blockIdx.x * blockDim.x + threadIdx.x;
  if (i < NN) {
    int r = rowptr[i] + part[i >> 8];
    rowptr[i] = r;
    pos[i] = r;
  }
  if (i == 0) rowptr[NN] = ET;
}

__global__ void scatter_k(const int* __restrict__ ei, int* __restrict__ pos,
                          int* __restrict__ srcs) {
  int e = blockIdx.x * blockDim.x + threadIdx.x;
  if (e >= ET) return;
  int s, d;
  if (e < NE) { s = ei[e]; d = ei[NE + e]; } else { s = d = e - NE; }
  int p = atomicAdd(&pos[d], 1);
  srcs[p] = s;
}

// ---------------- fused GAT aggregation (single pass, no max-shift) ----------------
template <int H, int C>
__global__ __launch_bounds__(128) void gat_agg_k(
    const int* __restrict__ rowptr, const int* __restrict__ srcs,
    const float* __restrict__ as, const float* __restrict__ ad,
    const unsigned short* __restrict__ h2, const float* __restrict__ bvec,
    float* __restrict__ y) {
  const int d = blockIdx.x;
  const int t = threadIdx.x;  // channel
  const int r0 = rowptr[d], r1 = rowptr[d + 1];

  __shared__ int ssh[128];
  __shared__ float exsh[128 * H];
  __shared__ float dred[2 * H];

  float adl[H];
#pragma unroll
  for (int hh = 0; hh < H; hh++) adl[hh] = ad[d * H + hh];

  const int hc = t / C;
  float acc = 0.f;
  float dsum[H];
#pragma unroll
  for (int hh = 0; hh < H; hh++) dsum[hh] = 0.f;

  for (int base = r0; base < r1; base += 128) {
    int cnt = min(128, r1 - base);
    if (t < cnt) {
      int s = srcs[base + t];
      ssh[t] = s;
#pragma unroll
      for (int hh = 0; hh < H; hh++) {
        float lg = as[s * H + hh] + adl[hh];
        lg = lg > 0.f ? lg : 0.2f * lg;
        float ex = __expf(lg);
        exsh[t * H + hh] = ex;
        dsum[hh] += ex;
      }
    }
    __syncthreads();
    for (int jj = 0; jj < cnt; jj++) {
      float hv = bf16tof(h2[(size_t)ssh[jj] * 128 + t]);
      acc += exsh[jj * H + hc] * hv;
    }
    __syncthreads();
  }

#pragma unroll
  for (int hh = 0; hh < H; hh++) {
    float v = dsum[hh];
#pragma unroll
    for (int off = 1; off < 64; off <<= 1) v += __shfl_xor(v, off);
    if ((t & 63) == 0) dred[(t >> 6) * H + hh] = v;
  }
  __syncthreads();
  float denom = dred[hc] + dred[H + hc] + 1e-16f;
  y[(size_t)d * 128 + t] = acc / denom + bvec[t];
}

// ---------------- BN ----------------
__global__ __launch_bounds__(256) void bn_stats_k(const float* __restrict__ y,
                                                  float* __restrict__ bnred) {
  __shared__ float red[256];
  int c = threadIdx.x & 127;
  int sub = threadIdx.x >> 7;
  int n0 = blockIdx.x * 64;
  float s1 = 0.f, s2 = 0.f;
  for (int k = 0; k < 32; k++) {
    int n = n0 + sub + k * 2;
    if (n < NN) {
      float v = y[(size_t)n * 128 + c];
      s1 += v;
      s2 += v * v;
    }
  }
  red[threadIdx.x] = s1;
  __syncthreads();
  if (sub == 0) atomicAdd(&bnred[c], s1 + red[threadIdx.x + 128]);
  __syncthreads();
  red[threadIdx.x] = s2;
  __syncthreads();
  if (sub == 0) atomicAdd(&bnred[128 + c], s2 + red[threadIdx.x + 128]);
}

__global__ void bn2_k(const float* __restrict__ bnred, const float* __restrict__ g,
                      const float* __restrict__ be, float* __restrict__ scale,
                      float* __restrict__ shift) {
  int c = threadIdx.x;
  float mean = bnred[c] / (float)NN;
  float var = bnred[128 + c] / (float)NN - mean * mean;
  float inv = rsqrtf(var + 1e-5f);
  float sc = g[c] * inv;
  scale[c] = sc;
  shift[c] = be[c] - mean * sc;
}

__global__ void bn3_k(const float* __restrict__ y, const float* __restrict__ scale,
                      const float* __restrict__ shift, float* __restrict__ out) {
  int i = blockIdx.x * blockDim.x + threadIdx.x;
  if (i >= NN * 128) return;
  int c = i & 127;
  float v = y[i] * scale[c] + shift[c];
  out[i] = v > 0.f ? v : 0.f;
}

extern "C" void kernel_launch(void* const* d_in, const int* in_sizes, int n_in,
                              void* d_out, int out_size, void* d_ws, size_t ws_size,
                              hipStream_t stream) {
  (void)in_sizes; (void)n_in; (void)out_size; (void)ws_size;
  const float* x = (const float*)d_in[0];
  const int* ei = (const int*)d_in[1];
  const float* W1 = (const float*)d_in[2];
  const float* as1 = (const float*)d_in[3];
  const float* ad1 = (const float*)d_in[4];
  const float* b1 = (const float*)d_in[5];
  const float* g1 = (const float*)d_in[6];
  const float* be1 = (const float*)d_in[7];
  const float* W2 = (const float*)d_in[8];
  const float* as2 = (const float*)d_in[9];
  const float* ad2 = (const float*)d_in[10];
  const float* b2 = (const float*)d_in[11];
  const float* g2 = (const float*)d_in[12];
  const float* be2 = (const float*)d_in[13];
  const float* W3 = (const float*)d_in[14];
  const float* as3 = (const float*)d_in[15];
  const float* ad3 = (const float*)d_in[16];
  const float* b3 = (const float*)d_in[17];
  const float* g3 = (const float*)d_in[18];
  const float* be3 = (const float*)d_in[19];

  float* Y = (float*)d_ws;                         // [NN*128] fp32
  unsigned short* h2 = (unsigned short*)(Y + (size_t)NN * 128);  // [NN*128] bf16
  float* asrc = (float*)(h2 + (size_t)NN * 128);   // [NN*4]
  float* adst = asrc + (size_t)NN * 4;             // [NN*4]
  float* bnred = adst + (size_t)NN * 4;            // [256]
  float* scale = bnred + 256;                      // [128]
  float* shift = scale + 128;                      // [128]
  int* rowptr = (int*)(shift + 128);               // [NN+1]
  int* cnt = rowptr + NN + 2;                      // [NN]
  int* pos = cnt + NN;                             // [NN]
  int* part = pos + NN;                            // [512]
  int* srcs = part + 512;                          // [ET]

  const int GB = (NN + 63) / 64;  // 1563

  // ---- CSR build (shared across layers) ----
  init_cnt_k<<<(NN + 255) / 256, 256, 0, stream>>>(cnt);
  hist_k<<<(NE + 255) / 256, 256, 0, stream>>>(ei, cnt);
  scan1_k<<<NB, 256, 0, stream>>>(cnt, rowptr, part);
  scan2_k<<<1, 512, 0, stream>>>(part);
  scan3_k<<<(NN + 255) / 256, 256, 0, stream>>>(rowptr, part, pos);
  scatter_k<<<(ET + 255) / 256, 256, 0, stream>>>(ei, pos, srcs);

  // ---- Layer 1 ----
  gemm_fused_k<64, 4, false><<<GB, 256, 0, stream>>>(x, W1, nullptr, nullptr,
                                                     as1, ad1, h2, asrc, adst);
  gat_agg_k<4, 32><<<NN, 128, 0, stream>>>(rowptr, srcs, asrc, adst, h2, b1, Y);
  hipMemsetAsync(bnred, 0, 256 * sizeof(float), stream);
  bn_stats_k<<<GB, 256, 0, stream>>>(Y, bnred);
  bn2_k<<<1, 128, 0, stream>>>(bnred, g1, be1, scale, shift);

  // ---- Layer 2 (BN applied inside gemm) ----
  gemm_fused_k<128, 4, true><<<GB, 256, 0, stream>>>(Y, W2, scale, shift,
                                                     as2, ad2, h2, asrc, adst);
  gat_agg_k<4, 32><<<NN, 128, 0, stream>>>(rowptr, srcs, asrc, adst, h2, b2, Y);
  hipMemsetAsync(bnred, 0, 256 * sizeof(float), stream);
  bn_stats_k<<<GB, 256, 0, stream>>>(Y, bnred);
  bn2_k<<<1, 128, 0, stream>>>(bnred, g2, be2, scale, shift);

  // ---- Layer 3 (H=1) ----
  gemm_fused_k<128, 1, true><<<GB, 256, 0, stream>>>(Y, W3, scale, shift,
                                                     as3, ad3, h2, asrc, adst);
  gat_agg_k<1, 128><<<NN, 128, 0, stream>>>(rowptr, srcs, asrc, adst, h2, b3, Y);
  hipMemsetAsync(bnred, 0, 256 * sizeof(float), stream);
  bn_stats_k<<<GB, 256, 0, stream>>>(Y, bnred);
  bn2_k<<<1, 128, 0, stream>>>(bnred, g3, be3, scale, shift);
  bn3_k<<<(NN * 128 + 255) / 256, 256, 0, stream>>>(Y, scale, shift, (float*)d_out);
}

// Round 4
// 712.399 us; speedup vs baseline: 13.3428x; 1.3605x over previous
//
#include <hip/hip_runtime.h>
#include <math.h>

#define NN 100000
#define NE 1600000
#define ET (NN + NE)
#define NB ((NN + 255) / 256)  // scan blocks = 391

typedef __attribute__((ext_vector_type(8))) __bf16 bf16x8;
typedef __attribute__((ext_vector_type(4))) float f32x4;

__device__ __forceinline__ unsigned short bf16rne(float f) {
  unsigned u = __float_as_uint(f);
  unsigned r = u + 0x7fffu + ((u >> 16) & 1u);
  return (unsigned short)(r >> 16);
}
__device__ __forceinline__ float bf16lo(unsigned u) {
  return __uint_as_float(u << 16);
}
__device__ __forceinline__ float bf16hi(unsigned u) {
  return __uint_as_float(u & 0xffff0000u);
}

// ---------------- fp32 -> bf16 cast ----------------
__global__ __launch_bounds__(256) void castbf_k(const float* __restrict__ in,
                                                unsigned short* __restrict__ out,
                                                int n4) {
  int i = blockIdx.x * 256 + threadIdx.x;
  if (i >= n4) return;
  float4 v = *(const float4*)(in + (size_t)i * 4);
  ushort4 u;
  u.x = bf16rne(v.x); u.y = bf16rne(v.y); u.z = bf16rne(v.z); u.w = bf16rne(v.w);
  *(ushort4*)(out + (size_t)i * 4) = u;
}

// ---------------- BN apply + ReLU + bf16 cast ----------------
__global__ __launch_bounds__(256) void bnc_k(const float* __restrict__ y,
                                             const float* __restrict__ scale,
                                             const float* __restrict__ shift,
                                             unsigned short* __restrict__ xb) {
  int i = blockIdx.x * 256 + threadIdx.x;  // float4 index over NN*128/4
  if (i >= NN * 32) return;
  int c = (i * 4) & 127;
  float4 v = *(const float4*)(y + (size_t)i * 4);
  float4 sc = *(const float4*)(scale + c);
  float4 sh = *(const float4*)(shift + c);
  ushort4 u;
  u.x = bf16rne(fmaxf(fmaf(v.x, sc.x, sh.x), 0.f));
  u.y = bf16rne(fmaxf(fmaf(v.y, sc.y, sh.y), 0.f));
  u.z = bf16rne(fmaxf(fmaf(v.z, sc.z, sh.z), 0.f));
  u.w = bf16rne(fmaxf(fmaf(v.w, sc.w, sh.w), 0.f));
  *(ushort4*)(xb + (size_t)i * 4) = u;
}

// ---------------- MFMA GEMM: h2 = bf16(xb @ W) + fused alpha dots ----------------
// 64 rows x 128 cols per block, 256 threads = 4 waves, each wave 16 rows.
// LDS XOR-swizzle (T2): byte ^= (row&7)<<4 keeps 16B alignment, kills bank conflicts.
template <int K, int H>
__global__ __launch_bounds__(256) void gemm_mfma_k(
    const unsigned short* __restrict__ xb, const float* __restrict__ W,
    const float* __restrict__ a_s, const float* __restrict__ a_d,
    unsigned short* __restrict__ h2, float* __restrict__ os,
    float* __restrict__ od) {
  __shared__ unsigned short xs[64 * K];
  __shared__ unsigned short Wt[128 * K];
  const int t = threadIdx.x;
  const int w = t >> 6;
  const int l = t & 63;
  const int l15 = l & 15, g = l >> 4;
  const int row0 = blockIdx.x * 64;

  // stage Wt[c][k] = bf16(W[k*128+c]), swizzled
  for (int idx = t; idx < K * 128; idx += 256) {
    int k = idx >> 7, c = idx & 127;
    unsigned byteoff = ((unsigned)(c * K + k) * 2u) ^ ((unsigned)(c & 7) << 4);
    *(unsigned short*)((char*)Wt + byteoff) = bf16rne(W[idx]);
  }
  // stage xs rows (bf16 global, 16B chunks), swizzled
  for (int idx = t; idx < 64 * (K / 8); idx += 256) {
    int r = idx / (K / 8);
    int c8 = (idx % (K / 8)) * 8;
    int grow = row0 + r;
    uint4 v = {0u, 0u, 0u, 0u};
    if (grow < NN) v = *(const uint4*)(xb + (size_t)grow * K + c8);
    unsigned byteoff = ((unsigned)(r * K + c8) * 2u) ^ ((unsigned)(r & 7) << 4);
    *(uint4*)((char*)xs + byteoff) = v;
  }
  __syncthreads();

  f32x4 acc[8];
#pragma unroll
  for (int ct = 0; ct < 8; ct++) acc[ct] = {0.f, 0.f, 0.f, 0.f};

  const int R = w * 16 + l15;
#pragma unroll
  for (int kc = 0; kc < K; kc += 32) {
    bf16x8 a = *(const bf16x8*)((const char*)xs +
        ((((unsigned)(R * K + kc + 8 * g)) * 2u) ^ ((unsigned)(R & 7) << 4)));
#pragma unroll
    for (int ct = 0; ct < 8; ct++) {
      int c = ct * 16 + l15;
      bf16x8 b = *(const bf16x8*)((const char*)Wt +
          ((((unsigned)(c * K + kc + 8 * g)) * 2u) ^ ((unsigned)(c & 7) << 4)));
      acc[ct] = __builtin_amdgcn_mfma_f32_16x16x32_bf16(a, b, acc[ct], 0, 0, 0);
    }
  }

  // epilogue: bf16 store + alpha dots
  float as_l[8], ad_l[8];
#pragma unroll
  for (int ct = 0; ct < 8; ct++) {
    as_l[ct] = a_s[ct * 16 + l15];
    ad_l[ct] = a_d[ct * 16 + l15];
  }

#pragma unroll
  for (int r = 0; r < 4; r++) {
    int grow = row0 + w * 16 + 4 * g + r;
    bool ok = grow < NN;
    if (ok) {
#pragma unroll
      for (int ct = 0; ct < 8; ct++)
        h2[(size_t)grow * 128 + ct * 16 + l15] = bf16rne(acc[ct][r]);
    }
    if (H == 4) {
      float ps[4], pd[4];
#pragma unroll
      for (int hh = 0; hh < 4; hh++) {
        ps[hh] = acc[2 * hh][r] * as_l[2 * hh] + acc[2 * hh + 1][r] * as_l[2 * hh + 1];
        pd[hh] = acc[2 * hh][r] * ad_l[2 * hh] + acc[2 * hh + 1][r] * ad_l[2 * hh + 1];
      }
#pragma unroll
      for (int hh = 0; hh < 4; hh++) {
#pragma unroll
        for (int off = 1; off < 16; off <<= 1) {
          ps[hh] += __shfl_xor(ps[hh], off);
          pd[hh] += __shfl_xor(pd[hh], off);
        }
      }
      float vs = (l15 == 0) ? ps[0] : (l15 == 1) ? ps[1] : (l15 == 2) ? ps[2] : ps[3];
      float vd = (l15 == 0) ? pd[0] : (l15 == 1) ? pd[1] : (l15 == 2) ? pd[2] : pd[3];
      if (ok && l15 < 4) {
        os[grow * 4 + l15] = vs;
        od[grow * 4 + l15] = vd;
      }
    } else {
      float ps = 0.f, pd = 0.f;
#pragma unroll
      for (int ct = 0; ct < 8; ct++) {
        ps += acc[ct][r] * as_l[ct];
        pd += acc[ct][r] * ad_l[ct];
      }
#pragma unroll
      for (int off = 1; off < 16; off <<= 1) {
        ps += __shfl_xor(ps, off);
        pd += __shfl_xor(pd, off);
      }
      if (ok && l15 == 0) {
        os[grow] = ps;
        od[grow] = pd;
      }
    }
  }
}

// ---------------- CSR build ----------------
__global__ void init_cnt_k(int* __restrict__ cnt) {
  int i = blockIdx.x * blockDim.x + threadIdx.x;
  if (i < NN) cnt[i] = 1;  // self-loop
}

__global__ void hist_k(const int* __restrict__ ei, int* __restrict__ cnt) {
  int e = blockIdx.x * blockDim.x + threadIdx.x;
  if (e < NE) atomicAdd(&cnt[ei[NE + e]], 1);
}

__global__ void scan1_k(const int* __restrict__ cnt, int* __restrict__ rowptr,
                        int* __restrict__ part) {
  __shared__ int tmp[256];
  int t = threadIdx.x;
  int i = blockIdx.x * 256 + t;
  int v = (i < NN) ? cnt[i] : 0;
  tmp[t] = v;
  __syncthreads();
  for (int off = 1; off < 256; off <<= 1) {
    int x = (t >= off) ? tmp[t - off] : 0;
    __syncthreads();
    tmp[t] += x;
    __syncthreads();
  }
  if (i < NN) rowptr[i] = tmp[t] - v;
  if (t == 255) part[blockIdx.x] = tmp[255];
}

__global__ void scan2_k(int* __restrict__ part) {
  __shared__ int tmp[512];
  int t = threadIdx.x;
  int v = (t < NB) ? part[t] : 0;
  tmp[t] = v;
  __syncthreads();
  for (int off = 1; off < 512; off <<= 1) {
    int x = (t >= off) ? tmp[t - off] : 0;
    __syncthreads();
    tmp[t] += x;
    __syncthreads();
  }
  if (t < NB) part[t] = tmp[t] - v;
}

__global__ void scan3_k(int* __restrict__ rowptr, const int* __restrict__ part,
                        int* __restrict__ pos) {
  int i = blockIdx.x * blockDim.x + threadIdx.x;
  if (i < NN) {
    int r = rowptr[i] + part[i >> 8];
    rowptr[i] = r;
    pos[i] = r;
  }
  if (i == 0) rowptr[NN] = ET;
}

__global__ void scatter_k(const int* __restrict__ ei, int* __restrict__ pos,
                          int* __restrict__ srcs) {
  int e = blockIdx.x * blockDim.x + threadIdx.x;
  if (e >= ET) return;
  int s, d;
  if (e < NE) { s = ei[e]; d = ei[NE + e]; } else { s = d = e - NE; }
  int p = atomicAdd(&pos[d], 1);
  srcs[p] = s;
}

// ---------------- GAT aggregation: one wave (64 thr) per dst node ----------------
// uint4 gather of bf16 h rows: 4 rows/wave-iter, 16 lanes x 8 channels each.
template <int H, int C>
__global__ __launch_bounds__(64) void gat_agg_k(
    const int* __restrict__ rowptr, const int* __restrict__ srcs,
    const float* __restrict__ as, const float* __restrict__ ad,
    const unsigned short* __restrict__ h2, const float* __restrict__ bvec,
    float* __restrict__ y) {
  const int d = blockIdx.x;
  const int t = threadIdx.x;
  const int l15 = t & 15, g4 = t >> 4;
  const int r0 = rowptr[d], r1 = rowptr[d + 1];

  __shared__ int ssh[64];
  __shared__ float exsh[64 * H];

  float adl[H];
#pragma unroll
  for (int hh = 0; hh < H; hh++) adl[hh] = ad[d * H + hh];

  const int hc = (l15 * 8) / C;
  float acc[8];
#pragma unroll
  for (int i = 0; i < 8; i++) acc[i] = 0.f;
  float dsum[H];
#pragma unroll
  for (int hh = 0; hh < H; hh++) dsum[hh] = 0.f;

  const uint4* h4 = (const uint4*)h2;

  for (int base = r0; base < r1; base += 64) {
    int cnt = min(64, r1 - base);
    __syncthreads();
    if (t < cnt) {
      int s = srcs[base + t];
      ssh[t] = s;
      if (H == 4) {
        float4 av = *(const float4*)(as + s * 4);
        float lg, ex;
        lg = av.x + adl[0]; lg = lg > 0.f ? lg : 0.2f * lg; ex = __expf(lg);
        exsh[t * 4 + 0] = ex; dsum[0] += ex;
        lg = av.y + adl[1]; lg = lg > 0.f ? lg : 0.2f * lg; ex = __expf(lg);
        exsh[t * 4 + 1] = ex; dsum[1] += ex;
        lg = av.z + adl[2]; lg = lg > 0.f ? lg : 0.2f * lg; ex = __expf(lg);
        exsh[t * 4 + 2] = ex; dsum[2] += ex;
        lg = av.w + adl[3]; lg = lg > 0.f ? lg : 0.2f * lg; ex = __expf(lg);
        exsh[t * 4 + 3] = ex; dsum[3] += ex;
      } else {
        float lg = as[s] + adl[0];
        lg = lg > 0.f ? lg : 0.2f * lg;
        float ex = __expf(lg);
        exsh[t] = ex;
        dsum[0] += ex;
      }
    }
    __syncthreads();
    int full = cnt >> 2;
#pragma unroll 2
    for (int jj = 0; jj < full; jj++) {
      int grp = jj * 4 + g4;
      int row = ssh[grp];
      uint4 u = h4[(size_t)row * 16 + l15];
      float wgt = exsh[grp * H + hc];
      acc[0] += wgt * bf16lo(u.x);
      acc[1] += wgt * bf16hi(u.x);
      acc[2] += wgt * bf16lo(u.y);
      acc[3] += wgt * bf16hi(u.y);
      acc[4] += wgt * bf16lo(u.z);
      acc[5] += wgt * bf16hi(u.z);
      acc[6] += wgt * bf16lo(u.w);
      acc[7] += wgt * bf16hi(u.w);
    }
    if (cnt & 3) {
      int grp = full * 4 + g4;
      if (g4 < (cnt & 3)) {
        int row = ssh[grp];
        uint4 u = h4[(size_t)row * 16 + l15];
        float wgt = exsh[grp * H + hc];
        acc[0] += wgt * bf16lo(u.x);
        acc[1] += wgt * bf16hi(u.x);
        acc[2] += wgt * bf16lo(u.y);
        acc[3] += wgt * bf16hi(u.y);
        acc[4] += wgt * bf16lo(u.z);
        acc[5] += wgt * bf16hi(u.z);
        acc[6] += wgt * bf16lo(u.w);
        acc[7] += wgt * bf16hi(u.w);
      }
    }
  }

#pragma unroll
  for (int i = 0; i < 8; i++) {
    acc[i] += __shfl_xor(acc[i], 16);
    acc[i] += __shfl_xor(acc[i], 32);
  }
#pragma unroll
  for (int hh = 0; hh < H; hh++) {
#pragma unroll
    for (int off = 1; off < 64; off <<= 1) dsum[hh] += __shfl_xor(dsum[hh], off);
  }

  if (t < 16) {
    float inv = 1.f / (dsum[hc] + 1e-16f);
    float4 b0 = *(const float4*)(bvec + t * 8);
    float4 b1 = *(const float4*)(bvec + t * 8 + 4);
    float4 o0, o1;
    o0.x = acc[0] * inv + b0.x;
    o0.y = acc[1] * inv + b0.y;
    o0.z = acc[2] * inv + b0.z;
    o0.w = acc[3] * inv + b0.w;
    o1.x = acc[4] * inv + b1.x;
    o1.y = acc[5] * inv + b1.y;
    o1.z = acc[6] * inv + b1.z;
    o1.w = acc[7] * inv + b1.w;
    *(float4*)(y + (size_t)d * 128 + t * 8) = o0;
    *(float4*)(y + (size_t)d * 128 + t * 8 + 4) = o1;
  }
}

// ---------------- BN ----------------
__global__ __launch_bounds__(256) void bn_stats_k(const float* __restrict__ y,
                                                  float* __restrict__ bnred) {
  __shared__ float red[256];
  int c = threadIdx.x & 127;
  int sub = threadIdx.x >> 7;
  int n0 = blockIdx.x * 64;
  float s1 = 0.f, s2 = 0.f;
  for (int k = 0; k < 32; k++) {
    int n = n0 + sub + k * 2;
    if (n < NN) {
      float v = y[(size_t)n * 128 + c];
      s1 += v;
      s2 += v * v;
    }
  }
  red[threadIdx.x] = s1;
  __syncthreads();
  if (sub == 0) atomicAdd(&bnred[c], s1 + red[threadIdx.x + 128]);
  __syncthreads();
  red[threadIdx.x] = s2;
  __syncthreads();
  if (sub == 0) atomicAdd(&bnred[128 + c], s2 + red[threadIdx.x + 128]);
}

__global__ void bn2_k(const float* __restrict__ bnred, const float* __restrict__ g,
                      const float* __restrict__ be, float* __restrict__ scale,
                      float* __restrict__ shift) {
  int c = threadIdx.x;
  float mean = bnred[c] / (float)NN;
  float var = bnred[128 + c] / (float)NN - mean * mean;
  float inv = rsqrtf(var + 1e-5f);
  float sc = g[c] * inv;
  scale[c] = sc;
  shift[c] = be[c] - mean * sc;
}

__global__ void bn3_k(const float* __restrict__ y, const float* __restrict__ scale,
                      const float* __restrict__ shift, float* __restrict__ out) {
  int i = blockIdx.x * blockDim.x + threadIdx.x;
  if (i >= NN * 128) return;
  int c = i & 127;
  float v = y[i] * scale[c] + shift[c];
  out[i] = v > 0.f ? v : 0.f;
}

extern "C" void kernel_launch(void* const* d_in, const int* in_sizes, int n_in,
                              void* d_out, int out_size, void* d_ws, size_t ws_size,
                              hipStream_t stream) {
  (void)in_sizes; (void)n_in; (void)out_size; (void)ws_size;
  const float* x = (const float*)d_in[0];
  const int* ei = (const int*)d_in[1];
  const float* W1 = (const float*)d_in[2];
  const float* as1 = (const float*)d_in[3];
  const float* ad1 = (const float*)d_in[4];
  const float* b1 = (const float*)d_in[5];
  const float* g1 = (const float*)d_in[6];
  const float* be1 = (const float*)d_in[7];
  const float* W2 = (const float*)d_in[8];
  const float* as2 = (const float*)d_in[9];
  const float* ad2 = (const float*)d_in[10];
  const float* b2 = (const float*)d_in[11];
  const float* g2 = (const float*)d_in[12];
  const float* be2 = (const float*)d_in[13];
  const float* W3 = (const float*)d_in[14];
  const float* as3 = (const float*)d_in[15];
  const float* ad3 = (const float*)d_in[16];
  const float* b3 = (const float*)d_in[17];
  const float* g3 = (const float*)d_in[18];
  const float* be3 = (const float*)d_in[19];

  float* Y = (float*)d_ws;                                   // [NN*128] fp32
  unsigned short* h2 = (unsigned short*)(Y + (size_t)NN * 128);  // [NN*128] bf16
  unsigned short* xb = h2 + (size_t)NN * 128;                // [NN*128] bf16
  float* asrc = (float*)(xb + (size_t)NN * 128);             // [NN*4]
  float* adst = asrc + (size_t)NN * 4;                       // [NN*4]
  float* bnred = adst + (size_t)NN * 4;                      // [256]
  float* scale = bnred + 256;                                // [128]
  float* shift = scale + 128;                                // [128]
  int* rowptr = (int*)(shift + 128);                         // [NN+1]
  int* cnt = rowptr + NN + 2;                                // [NN]
  int* pos = cnt + NN;                                       // [NN]
  int* part = pos + NN;                                      // [512]
  int* srcs = part + 512;                                    // [ET]

  const int GB64 = (NN + 63) / 64;   // 1563
  const int GBS = (NN + 63) / 64;    // bn_stats grid

  // ---- CSR build ----
  init_cnt_k<<<(NN + 255) / 256, 256, 0, stream>>>(cnt);
  hist_k<<<(NE + 255) / 256, 256, 0, stream>>>(ei, cnt);
  scan1_k<<<NB, 256, 0, stream>>>(cnt, rowptr, part);
  scan2_k<<<1, 512, 0, stream>>>(part);
  scan3_k<<<(NN + 255) / 256, 256, 0, stream>>>(rowptr, part, pos);
  scatter_k<<<(ET + 255) / 256, 256, 0, stream>>>(ei, pos, srcs);

  // ---- Layer 1 ----
  castbf_k<<<(NN * 16 + 255) / 256, 256, 0, stream>>>(x, xb, NN * 16);
  gemm_mfma_k<64, 4><<<GB64, 256, 0, stream>>>(xb, W1, as1, ad1, h2, asrc, adst);
  gat_agg_k<4, 32><<<NN, 64, 0, stream>>>(rowptr, srcs, asrc, adst, h2, b1, Y);
  hipMemsetAsync(bnred, 0, 256 * sizeof(float), stream);
  bn_stats_k<<<GBS, 256, 0, stream>>>(Y, bnred);
  bn2_k<<<1, 128, 0, stream>>>(bnred, g1, be1, scale, shift);

  // ---- Layer 2 ----
  bnc_k<<<(NN * 32 + 255) / 256, 256, 0, stream>>>(Y, scale, shift, xb);
  gemm_mfma_k<128, 4><<<GB64, 256, 0, stream>>>(xb, W2, as2, ad2, h2, asrc, adst);
  gat_agg_k<4, 32><<<NN, 64, 0, stream>>>(rowptr, srcs, asrc, adst, h2, b2, Y);
  hipMemsetAsync(bnred, 0, 256 * sizeof(float), stream);
  bn_stats_k<<<GBS, 256, 0, stream>>>(Y, bnred);
  bn2_k<<<1, 128, 0, stream>>>(bnred, g2, be2, scale, shift);

  // ---- Layer 3 ----
  bnc_k<<<(NN * 32 + 255) / 256, 256, 0, stream>>>(Y, scale, shift, xb);
  gemm_mfma_k<128, 1><<<GB64, 256, 0, stream>>>(xb, W3, as3, ad3, h2, asrc, adst);
  gat_agg_k<1, 128><<<NN, 64, 0, stream>>>(rowptr, srcs, asrc, adst, h2, b3, Y);
  hipMemsetAsync(bnred, 0, 256 * sizeof(float), stream);
  bn_stats_k<<<GBS, 256, 0, stream>>>(Y, bnred);
  bn2_k<<<1, 128, 0, stream>>>(bnred, g3, be3, scale, shift);
  bn3_k<<<(NN * 128 + 255) / 256, 256, 0, stream>>>(Y, scale, shift, (float*)d_out);
}